// Round 3
// baseline (132.972 us; speedup 1.0000x reference)
//
#include <hip/hip_runtime.h>

// AttentionNet N=128, a1=a2=64, f=2.
// 4 kernels; each stage kernel: grid 4*N=512, block 1024 (16 waves).
// Block covers 16 rows of one n; each row-pair is handled by TWO waves
// (k-halves [0,32) and [32,64)) merged via LDS -> 8 waves/SIMD at 2 blocks/CU.
// Inner loop per element: readlane + add + v_exp_f32 + add + v_rcp_f32 + add,
// operands register-resident (no LDS in hot loop).

constexpr int A   = 64;
constexpr int PAD = 65;   // 2-way bank aliasing = free
constexpr float L2E  = 1.4426950408889634f;
constexpr float EPSF = 1e-6f;

__device__ __forceinline__ float bcast(float v, int srcLane) {
    return __int_as_float(__builtin_amdgcn_readlane(__float_as_int(v), srcLane));
}

// Partial sigmoid-sums for rows row0, row0+1 over k in [k0, k0+32). lane <-> j.
template <typename LoadF>
__device__ __forceinline__ void att2_part(LoadF load, float W0, float W1, float bb,
                                          int row0, int k0,
                                          float& acc0, float& acc1)
{
    acc0 = 0.f; acc1 = 0.f;
#pragma unroll 1
    for (int c = 0; c < 2; ++c) {
        float ar[16], br[16];
#pragma unroll
        for (int kk = 0; kk < 16; ++kk) {
            float v = load(k0 + c * 16 + kk);
            // sigmoid(t) = 1/(1 + 2^(-t*log2e)); scales folded into ar/br.
            ar[kk] = -L2E * (W0 * v + bb);
            br[kk] = -L2E * (W1 * v);
        }
#pragma unroll
        for (int kk = 0; kk < 16; ++kk) {
            float z0 = ar[kk] + bcast(br[kk], row0);
            float z1 = ar[kk] + bcast(br[kk], row0 + 1);
            acc0 += __builtin_amdgcn_rcpf(1.0f + __builtin_amdgcn_exp2f(z0));
            acc1 += __builtin_amdgcn_rcpf(1.0f + __builtin_amdgcn_exp2f(z1));
        }
    }
}

// Merge k-halves through LDS, reduce across lanes, write m for 16 rows.
__device__ __forceinline__ void merge_stats(float acc0, float acc1,
                                            int pair, int khalf, int lane, int row0,
                                            float* __restrict__ part,  // [8][2][64]
                                            float* __restrict__ gm)
{
    if (khalf == 1) {
        part[(pair * 2 + 0) * A + lane] = acc0;
        part[(pair * 2 + 1) * A + lane] = acc1;
    }
    __syncthreads();
    if (khalf == 0) {
        acc0 += part[(pair * 2 + 0) * A + lane];
        acc1 += part[(pair * 2 + 1) * A + lane];
        float s0 = acc0, m0 = acc0, s1 = acc1, m1 = acc1;
#pragma unroll
        for (int off = 1; off < 64; off <<= 1) {
            s0 += __shfl_xor(s0, off, 64);
            m0 = fmaxf(m0, __shfl_xor(m0, off, 64));
            s1 += __shfl_xor(s1, off, 64);
            m1 = fmaxf(m1, __shfl_xor(m1, off, 64));
        }
        if (lane == 0) {
            // acc = 64*c; mean_j c = s/4096, max_j c = m/64.
            gm[row0]     = (s0 * (1.0f / 4096.0f)) / (m0 * (1.0f / 64.0f) + EPSF);
            gm[row0 + 1] = (s1 * (1.0f / 4096.0f)) / (m1 * (1.0f / 64.0f) + EPSF);
        }
    }
}

__device__ __forceinline__ float softmax64(float m, float sharp, float th, bool last)
{
    float v = fmaxf(0.f, m * sharp + th);
    float mx = v;
#pragma unroll
    for (int off = 1; off < 64; off <<= 1) mx = fmaxf(mx, __shfl_xor(mx, off, 64));
    float e = __expf(v - mx);
    float s = e;
#pragma unroll
    for (int off = 1; off < 64; off <<= 1) s += __shfl_xor(s, off, 64);
    float r = e / s;
    if (!last) {
        float rm = r;
#pragma unroll
        for (int off = 1; off < 64; off <<= 1) rm = fmaxf(rm, __shfl_xor(rm, off, 64));
        r = r / (rm + EPSF);
    }
    return r;
}

// ---- K1: stage B (rows over a1, k over a2, input h0) ----
__global__ __launch_bounds__(1024, 8)
void k_stageB(const float* __restrict__ x,
              const float* __restrict__ fcW, const float* __restrict__ fcb,
              const float* __restrict__ p1W, const float* __restrict__ p1b,
              float* __restrict__ m1)
{
    __shared__ float h0[A * PAD];
    __shared__ float part[16 * A];
    const int tid = threadIdx.x, lane = tid & 63, wv = tid >> 6;
    const int n = blockIdx.x >> 2, quarter = blockIdx.x & 3;
    const int pair = wv >> 1, khalf = wv & 1;
    const int row0 = quarter * 16 + pair * 2, k0 = khalf * 32;

    const float4* x0v = (const float4*)(x + (size_t)n * 2 * A * A);
    const float4* x1v = x0v + (A * A / 4);
    float4 a = x0v[tid];
    float4 c = x1v[tid];
    const float w00 = fcW[0], w01 = fcW[1], b0 = fcb[0];
    const int e = tid * 4, i = e >> 6, j = e & 63;
    float* q0 = &h0[i * PAD + j];
    q0[0] = fmaxf(0.f, w00 * a.x + w01 * c.x + b0);
    q0[1] = fmaxf(0.f, w00 * a.y + w01 * c.y + b0);
    q0[2] = fmaxf(0.f, w00 * a.z + w01 * c.z + b0);
    q0[3] = fmaxf(0.f, w00 * a.w + w01 * c.w + b0);
    __syncthreads();

    float acc0, acc1;
    att2_part([&](int k) { return h0[lane * PAD + k]; },
              p1W[0], p1W[1], p1b[0], row0, k0, acc0, acc1);
    merge_stats(acc0, acc1, pair, khalf, lane, row0, part, m1 + (size_t)n * A);
}

// ---- K2: stage C (rows over a2, k over a1; h1 pre-scaled by vec1) ----
__global__ __launch_bounds__(1024, 8)
void k_stageC(const float* __restrict__ x,
              const float* __restrict__ fcW, const float* __restrict__ fcb,
              const float* __restrict__ p1s, const float* __restrict__ p1t,
              const float* __restrict__ p2W, const float* __restrict__ p2b,
              const float* __restrict__ m1, float* __restrict__ m2)
{
    __shared__ float h1[A * PAD];
    __shared__ float part[16 * A];
    __shared__ float v1buf[A];
    const int tid = threadIdx.x, lane = tid & 63, wv = tid >> 6;
    const int n = blockIdx.x >> 2, quarter = blockIdx.x & 3;
    const int pair = wv >> 1, khalf = wv & 1;
    const int row0 = quarter * 16 + pair * 2, k0 = khalf * 32;

    const float4* x0v = (const float4*)(x + (size_t)n * 2 * A * A);
    const float4* x1v = x0v + (A * A / 4);
    float4 a = x0v[tid];
    float4 c = x1v[tid];

    if (tid < 64) v1buf[tid] = softmax64(m1[(size_t)n * A + tid], p1s[0], p1t[0], false);
    __syncthreads();

    const float w10 = fcW[2], w11 = fcW[3], b1 = fcb[1];
    const int e = tid * 4, i = e >> 6, j = e & 63;
    const float sc = v1buf[i];            // vec1 over a1 = tile row index
    float* q1 = &h1[i * PAD + j];
    q1[0] = fmaxf(0.f, w10 * a.x + w11 * c.x + b1) * sc;
    q1[1] = fmaxf(0.f, w10 * a.y + w11 * c.y + b1) * sc;
    q1[2] = fmaxf(0.f, w10 * a.z + w11 * c.z + b1) * sc;
    q1[3] = fmaxf(0.f, w10 * a.w + w11 * c.w + b1) * sc;
    __syncthreads();

    float acc0, acc1;
    att2_part([&](int k) { return h1[k * PAD + lane]; },   // transposed access
              p2W[0], p2W[1], p2b[0], row0, k0, acc0, acc1);
    merge_stats(acc0, acc1, pair, khalf, lane, row0, part, m2 + (size_t)n * A);
}

// ---- K3: stage D (h0 pre-scaled by vec1[i]*vec2[j]) ----
__global__ __launch_bounds__(1024, 8)
void k_stageD(const float* __restrict__ x,
              const float* __restrict__ fcW, const float* __restrict__ fcb,
              const float* __restrict__ p1s, const float* __restrict__ p1t,
              const float* __restrict__ p2s, const float* __restrict__ p2t,
              const float* __restrict__ oW,  const float* __restrict__ ob,
              const float* __restrict__ m1,  const float* __restrict__ m2,
              float* __restrict__ m3)
{
    __shared__ float h0[A * PAD];
    __shared__ float part[16 * A];
    __shared__ float v1buf[A], v2buf[A];
    const int tid = threadIdx.x, lane = tid & 63, wv = tid >> 6;
    const int n = blockIdx.x >> 2, quarter = blockIdx.x & 3;
    const int pair = wv >> 1, khalf = wv & 1;
    const int row0 = quarter * 16 + pair * 2, k0 = khalf * 32;

    const float4* x0v = (const float4*)(x + (size_t)n * 2 * A * A);
    const float4* x1v = x0v + (A * A / 4);
    float4 a = x0v[tid];
    float4 c = x1v[tid];

    if (tid < 64)       v1buf[tid]      = softmax64(m1[(size_t)n * A + tid],      p1s[0], p1t[0], false);
    else if (tid < 128) v2buf[tid - 64] = softmax64(m2[(size_t)n * A + tid - 64], p2s[0], p2t[0], false);
    __syncthreads();

    const float w00 = fcW[0], w01 = fcW[1], b0 = fcb[0];
    const int e = tid * 4, i = e >> 6, j = e & 63;
    const float sc = v1buf[i];
    float* q0 = &h0[i * PAD + j];
    q0[0] = fmaxf(0.f, w00 * a.x + w01 * c.x + b0) * sc * v2buf[j];
    q0[1] = fmaxf(0.f, w00 * a.y + w01 * c.y + b0) * sc * v2buf[j + 1];
    q0[2] = fmaxf(0.f, w00 * a.z + w01 * c.z + b0) * sc * v2buf[j + 2];
    q0[3] = fmaxf(0.f, w00 * a.w + w01 * c.w + b0) * sc * v2buf[j + 3];
    __syncthreads();

    float acc0, acc1;
    att2_part([&](int k) { return h0[lane * PAD + k]; },
              oW[0], oW[1], ob[0], row0, k0, acc0, acc1);
    merge_stats(acc0, acc1, pair, khalf, lane, row0, part, m3 + (size_t)n * A);
}

// ---- K4: final softmax -> out ----
__global__ __launch_bounds__(64, 1)
void k_final(const float* __restrict__ m3,
             const float* __restrict__ os, const float* __restrict__ ot,
             float* __restrict__ out)
{
    const int n = blockIdx.x, lane = threadIdx.x;
    out[(size_t)n * A + lane] = softmax64(m3[(size_t)n * A + lane], os[0], ot[0], true);
}

extern "C" void kernel_launch(void* const* d_in, const int* in_sizes, int n_in,
                              void* d_out, int out_size, void* d_ws, size_t ws_size,
                              hipStream_t stream)
{
    (void)n_in; (void)out_size; (void)ws_size;
    const float* x   = (const float*)d_in[0];
    const float* fcW = (const float*)d_in[1];
    const float* fcb = (const float*)d_in[2];
    const float* p1W = (const float*)d_in[3];
    const float* p1b = (const float*)d_in[4];
    const float* p1s = (const float*)d_in[5];
    const float* p1t = (const float*)d_in[6];
    const float* p2W = (const float*)d_in[7];
    const float* p2b = (const float*)d_in[8];
    const float* p2s = (const float*)d_in[9];
    const float* p2t = (const float*)d_in[10];
    const float* oW  = (const float*)d_in[11];
    const float* ob  = (const float*)d_in[12];
    const float* os  = (const float*)d_in[13];
    const float* ot  = (const float*)d_in[14];
    float* out = (float*)d_out;

    const int N = in_sizes[0] / (2 * A * A);   // 128
    float* ws = (float*)d_ws;
    float* m1 = ws;
    float* m2 = ws + (size_t)N * A;
    float* m3 = ws + (size_t)2 * N * A;

    k_stageB<<<4 * N, 1024, 0, stream>>>(x, fcW, fcb, p1W, p1b, m1);
    k_stageC<<<4 * N, 1024, 0, stream>>>(x, fcW, fcb, p1s, p1t, p2W, p2b, m1, m2);
    k_stageD<<<4 * N, 1024, 0, stream>>>(x, fcW, fcb, p1s, p1t, p2s, p2t, oW, ob, m1, m2, m3);
    k_final<<<N, 64, 0, stream>>>(m3, os, ot, out);
}

// Round 4
// 112.743 us; speedup vs baseline: 1.1794x; 1.1794x over previous
//
#include <hip/hip_runtime.h>

// AttentionNet N=128, a1=a2=64, f=2.
// R4: factorized sigmoid — sigma(w0*xj + w1*xi + b) = 1/(1 + p[j,k]*q[i,k])
// with p,q = exp2(-log2e * ...) precomputed ONCE per block into LDS.
// Inner loop per element: readlane(q_i) + v_fma(p*q+1) + v_rcp + add.
// Grid 2N=256 (1 block/CU), block 1024 = 16 waves, 2 rows/wave, full k.

constexpr int A   = 64;
constexpr int PAD = 65;   // 2-way bank aliasing = free
constexpr float L2E  = 1.4426950408889634f;
constexpr float EPSF = 1e-6f;

__device__ __forceinline__ float bcast(float v, int srcLane) {
    return __int_as_float(__builtin_amdgcn_readlane(__float_as_int(v), srcLane));
}
__device__ __forceinline__ float rcpf(float v) { return __builtin_amdgcn_rcpf(v); }
__device__ __forceinline__ float ex2(float v)  { return __builtin_amdgcn_exp2f(v); }

// Accumulate c-row stats for rows row0,row0+1 (lane <-> column j).
// prow/qrow point at this lane's row in the p/q LDS tiles.
__device__ __forceinline__ void att2(const float* __restrict__ prow,
                                     const float* __restrict__ qrow,
                                     int row0, int lane,
                                     float* __restrict__ gm)
{
    float acc0 = 0.f, acc1 = 0.f;
#pragma unroll 1
    for (int c = 0; c < 4; ++c) {
        float pk[16], qk[16];
#pragma unroll
        for (int t = 0; t < 16; ++t) {
            pk[t] = prow[c * 16 + t];
            qk[t] = qrow[c * 16 + t];
        }
#pragma unroll
        for (int t = 0; t < 16; ++t) {
            float q0 = bcast(qk[t], row0);
            float q1 = bcast(qk[t], row0 + 1);
            acc0 += rcpf(fmaf(pk[t], q0, 1.0f));
            acc1 += rcpf(fmaf(pk[t], q1, 1.0f));
        }
    }
    float s0 = acc0, m0 = acc0, s1 = acc1, m1v = acc1;
#pragma unroll
    for (int off = 1; off < 64; off <<= 1) {
        s0 += __shfl_xor(s0, off, 64);
        m0 = fmaxf(m0, __shfl_xor(m0, off, 64));
        s1 += __shfl_xor(s1, off, 64);
        m1v = fmaxf(m1v, __shfl_xor(m1v, off, 64));
    }
    if (lane == 0) {
        // acc = 64*c; mean_j c = s/4096, max_j c = m/64.
        gm[row0]     = (s0 * (1.0f / 4096.0f)) / (m0 * (1.0f / 64.0f) + EPSF);
        gm[row0 + 1] = (s1 * (1.0f / 4096.0f)) / (m1v * (1.0f / 64.0f) + EPSF);
    }
}

__device__ __forceinline__ float softmax64(float m, float sharp, float th, bool last)
{
    float v = fmaxf(0.f, m * sharp + th);
    float mx = v;
#pragma unroll
    for (int off = 1; off < 64; off <<= 1) mx = fmaxf(mx, __shfl_xor(mx, off, 64));
    float e = __expf(v - mx);
    float s = e;
#pragma unroll
    for (int off = 1; off < 64; off <<= 1) s += __shfl_xor(s, off, 64);
    float r = e / s;
    if (!last) {
        float rm = r;
#pragma unroll
        for (int off = 1; off < 64; off <<= 1) rm = fmaxf(rm, __shfl_xor(rm, off, 64));
        r = r / (rm + EPSF);
    }
    return r;
}

// ---- K1: stage B (X = h0, row-major) ----
__global__ __launch_bounds__(1024, 1)
void k_stageB(const float* __restrict__ x,
              const float* __restrict__ fcW, const float* __restrict__ fcb,
              const float* __restrict__ p1W, const float* __restrict__ p1b,
              float* __restrict__ m1)
{
    __shared__ float pL[A * PAD];
    __shared__ float qL[A * PAD];
    const int tid = threadIdx.x, lane = tid & 63, wv = tid >> 6;
    const int n = blockIdx.x >> 1, half = blockIdx.x & 1;

    const float4* x0v = (const float4*)(x + (size_t)n * 2 * A * A);
    const float4* x1v = x0v + (A * A / 4);
    float4 a = x0v[tid];
    float4 c = x1v[tid];
    const float w00 = fcW[0], w01 = fcW[1], b0 = fcb[0];
    const float W0 = p1W[0], W1 = p1W[1], bb = p1b[0];
    const int e = tid * 4, i = e >> 6, j = e & 63;
    float hv[4] = { fmaxf(0.f, w00 * a.x + w01 * c.x + b0),
                    fmaxf(0.f, w00 * a.y + w01 * c.y + b0),
                    fmaxf(0.f, w00 * a.z + w01 * c.z + b0),
                    fmaxf(0.f, w00 * a.w + w01 * c.w + b0) };
#pragma unroll
    for (int t = 0; t < 4; ++t) {
        pL[i * PAD + j + t] = ex2(-L2E * (W0 * hv[t] + bb));
        qL[i * PAD + j + t] = ex2(-L2E * (W1 * hv[t]));
    }
    __syncthreads();

    const int row0 = half * 32 + wv * 2;
    att2(pL + lane * PAD, qL + lane * PAD, row0, lane, m1 + (size_t)n * A);
}

// ---- K2: stage C (X = transpose(h1 * vec1); p/q written transposed) ----
__global__ __launch_bounds__(1024, 1)
void k_stageC(const float* __restrict__ x,
              const float* __restrict__ fcW, const float* __restrict__ fcb,
              const float* __restrict__ p1s, const float* __restrict__ p1t,
              const float* __restrict__ p2W, const float* __restrict__ p2b,
              const float* __restrict__ m1, float* __restrict__ m2)
{
    __shared__ float pL[A * PAD];
    __shared__ float qL[A * PAD];
    __shared__ float v1buf[A];
    const int tid = threadIdx.x, lane = tid & 63, wv = tid >> 6;
    const int n = blockIdx.x >> 1, half = blockIdx.x & 1;

    const float4* x0v = (const float4*)(x + (size_t)n * 2 * A * A);
    const float4* x1v = x0v + (A * A / 4);
    float4 a = x0v[tid];
    float4 c = x1v[tid];

    if (tid < 64) v1buf[tid] = softmax64(m1[(size_t)n * A + tid], p1s[0], p1t[0], false);
    __syncthreads();

    const float w10 = fcW[2], w11 = fcW[3], b1 = fcb[1];
    const float W0 = p2W[0], W1 = p2W[1], bb = p2b[0];
    const int e = tid * 4, i = e >> 6, j = e & 63;   // i: a1 row, j..j+3: a2 cols
    const float sc = v1buf[i];
    float hv[4] = { fmaxf(0.f, w10 * a.x + w11 * c.x + b1) * sc,
                    fmaxf(0.f, w10 * a.y + w11 * c.y + b1) * sc,
                    fmaxf(0.f, w10 * a.z + w11 * c.z + b1) * sc,
                    fmaxf(0.f, w10 * a.w + w11 * c.w + b1) * sc };
#pragma unroll
    for (int t = 0; t < 4; ++t) {   // X[j+t][i] = h1[i][j+t]*v1[i]  (transposed store)
        pL[(j + t) * PAD + i] = ex2(-L2E * (W0 * hv[t] + bb));
        qL[(j + t) * PAD + i] = ex2(-L2E * (W1 * hv[t]));
    }
    __syncthreads();

    const int row0 = half * 32 + wv * 2;
    att2(pL + lane * PAD, qL + lane * PAD, row0, lane, m2 + (size_t)n * A);
}

// ---- K3: stage D (X = h0 * vec1[i] * vec2[j], row-major) ----
__global__ __launch_bounds__(1024, 1)
void k_stageD(const float* __restrict__ x,
              const float* __restrict__ fcW, const float* __restrict__ fcb,
              const float* __restrict__ p1s, const float* __restrict__ p1t,
              const float* __restrict__ p2s, const float* __restrict__ p2t,
              const float* __restrict__ oW,  const float* __restrict__ ob,
              const float* __restrict__ m1,  const float* __restrict__ m2,
              float* __restrict__ m3)
{
    __shared__ float pL[A * PAD];
    __shared__ float qL[A * PAD];
    __shared__ float v1buf[A], v2buf[A];
    const int tid = threadIdx.x, lane = tid & 63, wv = tid >> 6;
    const int n = blockIdx.x >> 1, half = blockIdx.x & 1;

    const float4* x0v = (const float4*)(x + (size_t)n * 2 * A * A);
    const float4* x1v = x0v + (A * A / 4);
    float4 a = x0v[tid];
    float4 c = x1v[tid];

    if (tid < 64)       v1buf[tid]      = softmax64(m1[(size_t)n * A + tid],      p1s[0], p1t[0], false);
    else if (tid < 128) v2buf[tid - 64] = softmax64(m2[(size_t)n * A + tid - 64], p2s[0], p2t[0], false);
    __syncthreads();

    const float w00 = fcW[0], w01 = fcW[1], b0 = fcb[0];
    const float W0 = oW[0], W1 = oW[1], bb = ob[0];
    const int e = tid * 4, i = e >> 6, j = e & 63;
    const float sc = v1buf[i];
    float hv[4] = { fmaxf(0.f, w00 * a.x + w01 * c.x + b0) * sc * v2buf[j],
                    fmaxf(0.f, w00 * a.y + w01 * c.y + b0) * sc * v2buf[j + 1],
                    fmaxf(0.f, w00 * a.z + w01 * c.z + b0) * sc * v2buf[j + 2],
                    fmaxf(0.f, w00 * a.w + w01 * c.w + b0) * sc * v2buf[j + 3] };
#pragma unroll
    for (int t = 0; t < 4; ++t) {
        pL[i * PAD + j + t] = ex2(-L2E * (W0 * hv[t] + bb));
        qL[i * PAD + j + t] = ex2(-L2E * (W1 * hv[t]));
    }
    __syncthreads();

    const int row0 = half * 32 + wv * 2;
    att2(pL + lane * PAD, qL + lane * PAD, row0, lane, m3 + (size_t)n * A);
}

// ---- K4: final softmax -> out ----
__global__ __launch_bounds__(64, 1)
void k_final(const float* __restrict__ m3,
             const float* __restrict__ os, const float* __restrict__ ot,
             float* __restrict__ out)
{
    const int n = blockIdx.x, lane = threadIdx.x;
    out[(size_t)n * A + lane] = softmax64(m3[(size_t)n * A + lane], os[0], ot[0], true);
}

extern "C" void kernel_launch(void* const* d_in, const int* in_sizes, int n_in,
                              void* d_out, int out_size, void* d_ws, size_t ws_size,
                              hipStream_t stream)
{
    (void)n_in; (void)out_size; (void)ws_size;
    const float* x   = (const float*)d_in[0];
    const float* fcW = (const float*)d_in[1];
    const float* fcb = (const float*)d_in[2];
    const float* p1W = (const float*)d_in[3];
    const float* p1b = (const float*)d_in[4];
    const float* p1s = (const float*)d_in[5];
    const float* p1t = (const float*)d_in[6];
    const float* p2W = (const float*)d_in[7];
    const float* p2b = (const float*)d_in[8];
    const float* p2s = (const float*)d_in[9];
    const float* p2t = (const float*)d_in[10];
    const float* oW  = (const float*)d_in[11];
    const float* ob  = (const float*)d_in[12];
    const float* os  = (const float*)d_in[13];
    const float* ot  = (const float*)d_in[14];
    float* out = (float*)d_out;

    const int N = in_sizes[0] / (2 * A * A);   // 128
    float* ws = (float*)d_ws;
    float* m1 = ws;
    float* m2 = ws + (size_t)N * A;
    float* m3 = ws + (size_t)2 * N * A;

    k_stageB<<<2 * N, 1024, 0, stream>>>(x, fcW, fcb, p1W, p1b, m1);
    k_stageC<<<2 * N, 1024, 0, stream>>>(x, fcW, fcb, p1s, p1t, p2W, p2b, m1, m2);
    k_stageD<<<2 * N, 1024, 0, stream>>>(x, fcW, fcb, p1s, p1t, p2s, p2t, oW, ob, m1, m2, m3);
    k_final<<<N, 64, 0, stream>>>(m3, os, ot, out);
}